// Round 16
// baseline (127.551 us; speedup 1.0000x reference)
//
#include <hip/hip_runtime.h>
#include <hip/hip_bf16.h>
#include <stdint.h>

#define DIM 1024
#define NH 16
#define HD 64
#define BATCH 2
#define SEQ 2048
#define ROWS (BATCH*SEQ)   // 4096
#define NS 2               // KV splits (in-block)
#define CHUNK (SEQ/NS)     // 1024
#define NT (CHUNK/64)      // 16 tiles per chunk

typedef __attribute__((ext_vector_type(8))) short bf16x8;
typedef __attribute__((ext_vector_type(4))) float f32x4;
typedef __attribute__((ext_vector_type(16))) float f32x16;
typedef __attribute__((ext_vector_type(4))) unsigned short u16x4;
typedef __attribute__((ext_vector_type(4))) unsigned int u32x4;

static __device__ __forceinline__ unsigned short f2bf(float f) {
    union { float f; uint32_t u; } v; v.f = f;
    uint32_t u = v.u;
    uint32_t rnd = 0x7fffu + ((u >> 16) & 1u);   // RNE
    return (unsigned short)((u + rnd) >> 16);
}

static __device__ __forceinline__ unsigned cvt_pk_bf16(float lo, float hi) {
    unsigned r;
    asm("v_cvt_pk_bf16_f32 %0, %1, %2" : "=v"(r) : "v"(lo), "v"(hi));
    return r;
}

// ---------------- fused preprocessing: f32->bf16 casts + all 3 weight transposes ----------------
__global__ void k_pre(const float* __restrict__ tgt, const float* __restrict__ src,
                      unsigned short* __restrict__ tgt_b, unsigned short* __restrict__ src_b,
                      const float* __restrict__ Wq, const float* __restrict__ Wkv,
                      const float* __restrict__ Wo,
                      unsigned short* __restrict__ WqT, unsigned short* __restrict__ WkvT,
                      unsigned short* __restrict__ WoT) {
    __shared__ float tile[32][33];
    int blk = blockIdx.x;
    if (blk < 8192) {
        const float* in = (blk < 4096) ? tgt : src;
        unsigned short* out = (blk < 4096) ? tgt_b : src_b;
        int i = ((blk & 4095) * 256 + threadIdx.x) * 4;
        f32x4 v = *(const f32x4*)(in + i);
        u16x4 o;
        o.x = f2bf(v.x); o.y = f2bf(v.y); o.z = f2bf(v.z); o.w = f2bf(v.w);
        *(u16x4*)(out + i) = o;
        return;
    }
    int bp = blk - 8192;                 // 0..4095
    int bx = bp & 127, by = bp >> 7;     // bx: N-tile, by: K-tile
    const float* W; unsigned short* WT; int N, xb;
    if (bx < 32)      { W = Wq;  WT = WqT;  N = DIM;     xb = bx; }
    else if (bx < 96) { W = Wkv; WT = WkvT; N = 2 * DIM; xb = bx - 32; }
    else              { W = Wo;  WT = WoT;  N = DIM;     xb = bx - 96; }
    const int K = DIM;
    int nt = xb * 32, kt = by * 32;
    int x = threadIdx.x & 31, y = threadIdx.x >> 5;   // 32 x 8
    #pragma unroll
    for (int i = 0; i < 32; i += 8)
        tile[y + i][x] = W[(size_t)(kt + y + i) * N + nt + x];
    __syncthreads();
    #pragma unroll
    for (int i = 0; i < 32; i += 8)
        WT[(size_t)(nt + y + i) * K + kt + x] = f2bf(tile[x][y + i]);
}

// ---------------- fused q+kv GEMM + RMSNorm + RoPE + attention-layout pack ----------------
// Grid dim3(32, 24): blockIdx.x = m-block (XCD-localizes A panels), blockIdx.y = role/col.
__launch_bounds__(256, 3)
__global__ void k_gemm_qkv(const unsigned short* __restrict__ tgt_b,
                           const unsigned short* __restrict__ src_b,
                           const unsigned short* __restrict__ WqT,
                           const unsigned short* __restrict__ WkvT,
                           const float* __restrict__ tpos, const float* __restrict__ spos,
                           const float* __restrict__ qw, const float* __restrict__ kw,
                           unsigned short* __restrict__ q_a, unsigned short* __restrict__ k_f,
                           unsigned short* __restrict__ v_f) {
    __shared__ __align__(16) unsigned short As[128 * 64];
    __shared__ __align__(16) unsigned short Bs[128 * 64];
    const int tid  = threadIdx.x;
    const int wid  = tid >> 6, lane = tid & 63;
    const int l15  = lane & 15, l4 = lane >> 4;
    const int bx = blockIdx.y;                       // role/col selector
    const unsigned short* A;  const unsigned short* BT;  int n0;
    if (bx < 8) { A = tgt_b; BT = WqT;  n0 = bx * 128; }
    else        { A = src_b; BT = WkvT; n0 = (bx - 8) * 128; }
    const int K = DIM;
    const int m0 = blockIdx.x * 128;                 // m-block: XCD = blockIdx.x % 8
    const int wr = wid >> 1, wc = wid & 1;
    const int srow = lane >> 3, schunk = lane & 7;

    f32x4 acc[4][4] = {};

    for (int kt = 0; kt < K; kt += 64) {
        #pragma unroll
        for (int t = 0; t < 4; ++t) {
            int r  = (t * 4 + wid) * 8 + srow;          // tile row 0..127
            int ck = schunk ^ (r & 7);                  // pre-swizzled source chunk
            const unsigned short* ga = A  + (size_t)(m0 + r) * K + kt + ck * 8;
            const unsigned short* gb = BT + (size_t)(n0 + r) * K + kt + ck * 8;
            unsigned short* la = As + (t * 4 + wid) * 512 + lane * 8;  // linear dest
            unsigned short* lb = Bs + (t * 4 + wid) * 512 + lane * 8;
            __builtin_amdgcn_global_load_lds((const __attribute__((address_space(1))) void*)ga,
                                             (__attribute__((address_space(3))) void*)la, 16, 0, 0);
            __builtin_amdgcn_global_load_lds((const __attribute__((address_space(1))) void*)gb,
                                             (__attribute__((address_space(3))) void*)lb, 16, 0, 0);
        }
        __syncthreads();
        #pragma unroll
        for (int k0 = 0; k0 < 2; ++k0) {
            bf16x8 af[4], bfr[4];
            int kk = k0 * 32 + l4 * 8;
            #pragma unroll
            for (int i = 0; i < 4; ++i) {
                int ar = wr * 64 + i * 16 + l15;
                af[i]  = *(const bf16x8*)((const char*)As + ar * 128 + ((kk * 2) ^ ((ar & 7) << 4)));
                int br = wc * 64 + i * 16 + l15;
                bfr[i] = *(const bf16x8*)((const char*)Bs + br * 128 + ((kk * 2) ^ ((br & 7) << 4)));
            }
            #pragma unroll
            for (int i = 0; i < 4; ++i)
                #pragma unroll
                for (int j = 0; j < 4; ++j)
                    acc[i][j] = __builtin_amdgcn_mfma_f32_16x16x32_bf16(af[i], bfr[j], acc[i][j], 0, 0, 0);
        }
        __syncthreads();
    }

    // ---------- fused epilogue ----------
    const int colbase = n0 + wc * 64;                       // q/k: 0..1023 ; v: 1024..2047
    const int mode = (bx < 8) ? 0 : ((colbase < 1024) ? 1 : 2);

    if (mode == 2) {                                        // V: cast into fragment-linear v_f
        const int h = (colbase - 1024) >> 6;
        #pragma unroll
        for (int i = 0; i < 4; ++i)
            #pragma unroll
            for (int r = 0; r < 4; ++r) {
                int row = m0 + wr * 64 + i * 16 + l4 * 4 + r;
                int b = row >> 11, mm = row & (SEQ - 1);
                int bh = b * NH + h;
                int t = mm >> 6, ks = (mm >> 5) & 1, kc = (mm >> 4) & 1;
                int hiv = (mm >> 3) & 1, e = mm & 7;
                #pragma unroll
                for (int j = 0; j < 4; ++j) {
                    int dh = j >> 1, l31v = (j & 1) * 16 + l15;
                    size_t idx = (((((size_t)(bh * 32 + t) * 2 + ks) * 2 + kc) * 2 + dh) * 2 + hiv) * 256
                                 + l31v * 8 + e;
                    v_f[idx] = f2bf(acc[i][j][r]);
                }
            }
        return;
    }

    const float* pos = (mode == 0) ? tpos : spos;
    const float* wt  = (mode == 0) ? qw : kw;
    const int h = colbase >> 6;
    const float QS = (mode == 0) ? 0.18033688011112042f : 1.0f;  // log2(e)/8 folded into q
    const float eps = 1.1920928955078125e-7f;

    float w4[4];
    #pragma unroll
    for (int j = 0; j < 4; ++j) w4[j] = wt[j * 16 + l15];
    float invf0 = __expf(-(float)(2 * l15) * (1.0f / 64.0f) * 9.21034037198f);
    float invf1 = __expf(-(float)(2 * (16 + l15)) * (1.0f / 64.0f) * 9.21034037198f);

    #pragma unroll
    for (int i = 0; i < 4; ++i)
        #pragma unroll
        for (int r = 0; r < 4; ++r) {
            int row = m0 + wr * 64 + i * 16 + l4 * 4 + r;
            float v0 = acc[i][0][r], v1 = acc[i][1][r], v2 = acc[i][2][r], v3 = acc[i][3][r];
            float ssq = v0 * v0 + v1 * v1 + v2 * v2 + v3 * v3;
            ssq += __shfl_xor(ssq, 1, 64);
            ssq += __shfl_xor(ssq, 2, 64);
            ssq += __shfl_xor(ssq, 4, 64);
            ssq += __shfl_xor(ssq, 8, 64);
            float sc = rsqrtf(ssq * (1.0f / 64.0f) + eps);
            v0 *= sc * w4[0]; v1 *= sc * w4[1]; v2 *= sc * w4[2]; v3 *= sc * w4[3];
            float p = pos[row];
            float s0, c0, s1, c1;
            __sincosf(p * invf0, &s0, &c0);
            __sincosf(p * invf1, &s1, &c1);
            float o0 = (v0 * c0 - v2 * s0) * QS;    // d = l15
            float o1 = (v1 * c1 - v3 * s1) * QS;    // d = 16+l15
            float o2 = (v0 * s0 + v2 * c0) * QS;    // d = 32+l15
            float o3 = (v1 * s1 + v3 * c1) * QS;    // d = 48+l15
            int b = row >> 11, n = row & (SEQ - 1);
            if (mode == 0) {
                unsigned short* dst = q_a + ((size_t)(b * NH + h) * SEQ + n) * 64;
                dst[l15]      = f2bf(o0);
                dst[16 + l15] = f2bf(o1);
                dst[32 + l15] = f2bf(o2);
                dst[48 + l15] = f2bf(o3);
            } else {
                // K into fragment-linear k_f: idx((bh,t,ks,c,hi,l31,e)) ; d = j*16+l15
                int bh = b * NH + h;
                int t = n >> 6, ksn = (n >> 5) & 1, l31k = n & 31;
                int hik = l15 >> 3, e = l15 & 7;
                size_t base = ((size_t)(bh * 32 + t) * 2 + ksn) * 4;
                k_f[(base + 0) * 512 + hik * 256 + l31k * 8 + e] = f2bf(o0);
                k_f[(base + 1) * 512 + hik * 256 + l31k * 8 + e] = f2bf(o1);
                k_f[(base + 2) * 512 + hik * 256 + l31k * 8 + e] = f2bf(o2);
                k_f[(base + 3) * 512 + hik * 256 + l31k * 8 + e] = f2bf(o3);
            }
        }
}

// ---------------- o-GEMM: C[M][N] f32 = A[M][K] bf16 @ BT[N][K]^T ----------------
// Grid dim3(32, 8): blockIdx.x = m-block (XCD-localizes A panels).
__launch_bounds__(256)
__global__ void k_gemm_bt(const unsigned short* __restrict__ A,
                          const unsigned short* __restrict__ BT,
                          float* __restrict__ C, int M, int N, int K) {
    __shared__ __align__(16) unsigned short As[128 * 64];
    __shared__ __align__(16) unsigned short Bs[128 * 64];
    const int tid  = threadIdx.x;
    const int wid  = tid >> 6, lane = tid & 63;
    const int l15  = lane & 15, l4 = lane >> 4;
    const int m0 = blockIdx.x * 128, n0 = blockIdx.y * 128;
    const int wr = wid >> 1, wc = wid & 1;
    const int srow = lane >> 3, schunk = lane & 7;

    f32x4 acc[4][4] = {};

    for (int kt = 0; kt < K; kt += 64) {
        #pragma unroll
        for (int t = 0; t < 4; ++t) {
            int r  = (t * 4 + wid) * 8 + srow;
            int ck = schunk ^ (r & 7);
            const unsigned short* ga = A  + (size_t)(m0 + r) * K + kt + ck * 8;
            const unsigned short* gb = BT + (size_t)(n0 + r) * K + kt + ck * 8;
            unsigned short* la = As + (t * 4 + wid) * 512 + lane * 8;
            unsigned short* lb = Bs + (t * 4 + wid) * 512 + lane * 8;
            __builtin_amdgcn_global_load_lds((const __attribute__((address_space(1))) void*)ga,
                                             (__attribute__((address_space(3))) void*)la, 16, 0, 0);
            __builtin_amdgcn_global_load_lds((const __attribute__((address_space(1))) void*)gb,
                                             (__attribute__((address_space(3))) void*)lb, 16, 0, 0);
        }
        __syncthreads();
        #pragma unroll
        for (int k0 = 0; k0 < 2; ++k0) {
            bf16x8 af[4], bfr[4];
            int kk = k0 * 32 + l4 * 8;
            #pragma unroll
            for (int i = 0; i < 4; ++i) {
                int ar = wr * 64 + i * 16 + l15;
                af[i]  = *(const bf16x8*)((const char*)As + ar * 128 + ((kk * 2) ^ ((ar & 7) << 4)));
                int br = wc * 64 + i * 16 + l15;
                bfr[i] = *(const bf16x8*)((const char*)Bs + br * 128 + ((kk * 2) ^ ((br & 7) << 4)));
            }
            #pragma unroll
            for (int i = 0; i < 4; ++i)
                #pragma unroll
                for (int j = 0; j < 4; ++j)
                    acc[i][j] = __builtin_amdgcn_mfma_f32_16x16x32_bf16(af[i], bfr[j], acc[i][j], 0, 0, 0);
        }
        __syncthreads();
    }
    #pragma unroll
    for (int i = 0; i < 4; ++i) {
        int rb = m0 + wr * 64 + i * 16 + l4 * 4;
        #pragma unroll
        for (int j = 0; j < 4; ++j) {
            int col = n0 + wc * 64 + j * 16 + l15;
            #pragma unroll
            for (int r = 0; r < 4; ++r)
                C[(size_t)(rb + r) * N + col] = acc[i][j][r];
        }
    }
}

// ---------------- flash attention, fully fused (KV-split combined IN-BLOCK) ----------------
// v16 = verified R14 body + `#pragma unroll 2` on the t-loop: sacc is declared
// inside the loop, so unrolling gives the scheduler two independent score-chains
// per iteration (compiler-managed T15). Semantics preserved by construction --
// no hand-built register pipeline (3 such edits failed correctness).
__launch_bounds__(512, 2)
__global__ void k_attn_part(const unsigned short* __restrict__ q_a,
                            const unsigned short* __restrict__ k_f,
                            const unsigned short* __restrict__ v_f,
                            unsigned short* __restrict__ x_b) {
    __shared__ float LO[4][32][68];   // [pair][qrow][col]; cols 64..67 hold L: 64+2*qf+ns
    const int tid = threadIdx.x;
    const int wid = tid >> 6, lane = tid & 63;
    const int l31 = lane & 31, hi = lane >> 5;
    const int pid = wid & 3, ns = wid >> 2;
    const int blk = blockIdx.x;
    const int bh = blk & 31, qx = blk >> 5;   // bh in low 5 bits -> XCD-aligned
    const int q0 = qx * 256 + pid * 64;
    const unsigned short* qb = q_a + (size_t)bh * SEQ * 64;

    bf16x8 qfr[2][4];
    #pragma unroll
    for (int qf = 0; qf < 2; ++qf)
        #pragma unroll
        for (int c = 0; c < 4; ++c)
            qfr[qf][c] = *(const bf16x8*)(qb + (size_t)(q0 + qf * 32 + l31) * 64 + c * 16 + hi * 8);

    const bf16x8* kf8 = (const bf16x8*)k_f + ((size_t)bh * 32 + ns * NT) * 512;
    const bf16x8* vf8 = (const bf16x8*)v_f + ((size_t)bh * 32 + ns * NT) * 512;

    f32x16 oacc[2][2] = {};
    float lsum[2] = {0.f, 0.f};

    #pragma unroll 2
    for (int t = 0; t < NT; ++t) {
        const bf16x8* kt = kf8 + (size_t)t * 512;
        const bf16x8* vt = vf8 + (size_t)t * 512;

        bf16x8 kf[2][4];
        #pragma unroll
        for (int ks = 0; ks < 2; ++ks)
            #pragma unroll
            for (int c = 0; c < 4; ++c)
                kf[ks][c] = kt[((ks * 4 + c) * 2 + hi) * 32 + l31];

        f32x16 sacc[2][2] = {};   // [qf][ks]
        #pragma unroll
        for (int ks = 0; ks < 2; ++ks)
            #pragma unroll
            for (int c = 0; c < 4; ++c) {
                sacc[0][ks] = __builtin_amdgcn_mfma_f32_32x32x16_bf16(kf[ks][c], qfr[0][c], sacc[0][ks], 0, 0, 0);
                sacc[1][ks] = __builtin_amdgcn_mfma_f32_32x32x16_bf16(kf[ks][c], qfr[1][c], sacc[1][ks], 0, 0, 0);
            }

        #pragma unroll
        for (int ks = 0; ks < 2; ++ks)
            #pragma unroll
            for (int kc = 0; kc < 2; ++kc) {
                bf16x8 vf[2];
                #pragma unroll
                for (int dh = 0; dh < 2; ++dh)
                    vf[dh] = vt[(((ks * 2 + kc) * 2 + dh) * 2 + hi) * 32 + l31];
                #pragma unroll
                for (int qf = 0; qf < 2; ++qf) {
                    float p[8];
                    #pragma unroll
                    for (int j = 0; j < 8; ++j)
                        p[j] = __builtin_amdgcn_exp2f(sacc[qf][ks][kc * 8 + j]);
                    lsum[qf] += ((p[0] + p[1]) + (p[2] + p[3])) + ((p[4] + p[5]) + (p[6] + p[7]));
                    unsigned a0 = cvt_pk_bf16(p[0], p[1]);
                    unsigned a1 = cvt_pk_bf16(p[2], p[3]);
                    unsigned b0 = cvt_pk_bf16(p[4], p[5]);
                    unsigned b1 = cvt_pk_bf16(p[6], p[7]);
                    asm("v_permlane32_swap_b32 %0, %1" : "+v"(a0), "+v"(b0));
                    asm("v_permlane32_swap_b32 %0, %1" : "+v"(a1), "+v"(b1));
                    u32x4 w; w.x = a0; w.y = a1; w.z = b0; w.w = b1;
                    bf16x8 pa = __builtin_bit_cast(bf16x8, w);
                    #pragma unroll
                    for (int dh = 0; dh < 2; ++dh)
                        oacc[qf][dh] = __builtin_amdgcn_mfma_f32_32x32x16_bf16(pa, vf[dh], oacc[qf][dh], 0, 0, 0);
                }
            }
    }

    lsum[0] += __shfl_xor(lsum[0], 32, 64);
    lsum[1] += __shfl_xor(lsum[1], 32, 64);

    // ---- in-block NS combine ----
    if (hi == 0) {
        LO[pid][l31][64 + ns] = lsum[0];
        LO[pid][l31][66 + ns] = lsum[1];
    }
    const int b_ = bh >> 4, h_ = bh & 15;
    #pragma unroll
    for (int qf = 0; qf < 2; ++qf) {
        __syncthreads();
        if (ns == 1) {
            #pragma unroll
            for (int r = 0; r < 16; ++r) {
                int qrow = (r & 3) + 8 * (r >> 2) + 4 * hi;
                LO[pid][qrow][l31]      = oacc[qf][0][r];
                LO[pid][qrow][32 + l31] = oacc[qf][1][r];
            }
        }
        __syncthreads();
        if (ns == 0) {
            #pragma unroll
            for (int r = 0; r < 16; ++r) {
                int qrow = (r & 3) + 8 * (r >> 2) + 4 * hi;
                float Lt = LO[pid][qrow][64 + 2 * qf] + LO[pid][qrow][65 + 2 * qf];
                float rec = 1.0f / Lt;
                float o0 = (oacc[qf][0][r] + LO[pid][qrow][l31])      * rec;
                float o1 = (oacc[qf][1][r] + LO[pid][qrow][32 + l31]) * rec;
                int q = q0 + qf * 32 + qrow;
                unsigned short* dst = x_b + ((size_t)(b_ * SEQ + q)) * DIM + h_ * 64;
                dst[l31]      = f2bf(o0);
                dst[32 + l31] = f2bf(o1);
            }
        }
    }
}

extern "C" void kernel_launch(void* const* d_in, const int* in_sizes, int n_in,
                              void* d_out, int out_size, void* d_ws, size_t ws_size,
                              hipStream_t stream) {
    const float* tgt  = (const float*)d_in[0];
    const float* src  = (const float*)d_in[1];
    const float* tpos = (const float*)d_in[2];
    const float* spos = (const float*)d_in[3];
    const float* Wq   = (const float*)d_in[4];
    const float* Wkv  = (const float*)d_in[5];
    const float* Wo   = (const float*)d_in[6];
    const float* qw   = (const float*)d_in[7];
    const float* kw   = (const float*)d_in[8];
    float* out = (float*)d_out;
    char* ws = (char*)d_ws;

    // workspace map (MB): [0,8) x_b|tgt_b  [8,16) src_b  [16,18) WqT  [18,22) WkvT
    // [22,24) WoT  [88,96) q_a  [96,104) k_f  [104,112) v_f
    unsigned short* tgt_b = (unsigned short*)(ws);
    unsigned short* src_b = (unsigned short*)(ws + ( 8u << 20));
    unsigned short* WqT   = (unsigned short*)(ws + (16u << 20));
    unsigned short* WkvT  = (unsigned short*)(ws + (18u << 20));
    unsigned short* WoT   = (unsigned short*)(ws + (22u << 20));
    unsigned short* q_a   = (unsigned short*)(ws + (88u << 20));
    unsigned short* k_f   = (unsigned short*)(ws + (96u << 20));
    unsigned short* v_f   = (unsigned short*)(ws + (104u << 20));
    unsigned short* x_b   = (unsigned short*)(ws);                 // alias tgt_b (dead)

    k_pre<<<12288, 256, 0, stream>>>(tgt, src, tgt_b, src_b, Wq, Wkv, Wo, WqT, WkvT, WoT);
    k_gemm_qkv<<<dim3(32, 24), 256, 0, stream>>>(tgt_b, src_b, WqT, WkvT,
                                                 tpos, spos, qw, kw, q_a, k_f, v_f);
    k_attn_part<<<256, 512, 0, stream>>>(q_a, k_f, v_f, x_b);
    k_gemm_bt<<<dim3(32, 8), 256, 0, stream>>>(x_b, WoT, out, ROWS, DIM, DIM);
}

// Round 17
// 107.164 us; speedup vs baseline: 1.1902x; 1.1902x over previous
//
#include <hip/hip_runtime.h>
#include <hip/hip_bf16.h>
#include <stdint.h>

#define DIM 1024
#define NH 16
#define HD 64
#define BATCH 2
#define SEQ 2048
#define ROWS (BATCH*SEQ)   // 4096
#define NS 2               // KV splits (in-block)
#define CHUNK (SEQ/NS)     // 1024
#define NT (CHUNK/64)      // 16 tiles per chunk

typedef __attribute__((ext_vector_type(8))) short bf16x8;
typedef __attribute__((ext_vector_type(4))) float f32x4;
typedef __attribute__((ext_vector_type(16))) float f32x16;
typedef __attribute__((ext_vector_type(4))) unsigned short u16x4;
typedef __attribute__((ext_vector_type(4))) unsigned int u32x4;

static __device__ __forceinline__ unsigned short f2bf(float f) {
    union { float f; uint32_t u; } v; v.f = f;
    uint32_t u = v.u;
    uint32_t rnd = 0x7fffu + ((u >> 16) & 1u);   // RNE
    return (unsigned short)((u + rnd) >> 16);
}

static __device__ __forceinline__ unsigned cvt_pk_bf16(float lo, float hi) {
    unsigned r;
    asm("v_cvt_pk_bf16_f32 %0, %1, %2" : "=v"(r) : "v"(lo), "v"(hi));
    return r;
}

// ---------------- fused preprocessing: f32->bf16 casts + all 3 weight transposes ----------------
__global__ void k_pre(const float* __restrict__ tgt, const float* __restrict__ src,
                      unsigned short* __restrict__ tgt_b, unsigned short* __restrict__ src_b,
                      const float* __restrict__ Wq, const float* __restrict__ Wkv,
                      const float* __restrict__ Wo,
                      unsigned short* __restrict__ WqT, unsigned short* __restrict__ WkvT,
                      unsigned short* __restrict__ WoT) {
    __shared__ float tile[32][33];
    int blk = blockIdx.x;
    if (blk < 8192) {
        const float* in = (blk < 4096) ? tgt : src;
        unsigned short* out = (blk < 4096) ? tgt_b : src_b;
        int i = ((blk & 4095) * 256 + threadIdx.x) * 4;
        f32x4 v = *(const f32x4*)(in + i);
        u16x4 o;
        o.x = f2bf(v.x); o.y = f2bf(v.y); o.z = f2bf(v.z); o.w = f2bf(v.w);
        *(u16x4*)(out + i) = o;
        return;
    }
    int bp = blk - 8192;                 // 0..4095
    int bx = bp & 127, by = bp >> 7;     // bx: N-tile, by: K-tile
    const float* W; unsigned short* WT; int N, xb;
    if (bx < 32)      { W = Wq;  WT = WqT;  N = DIM;     xb = bx; }
    else if (bx < 96) { W = Wkv; WT = WkvT; N = 2 * DIM; xb = bx - 32; }
    else              { W = Wo;  WT = WoT;  N = DIM;     xb = bx - 96; }
    const int K = DIM;
    int nt = xb * 32, kt = by * 32;
    int x = threadIdx.x & 31, y = threadIdx.x >> 5;   // 32 x 8
    #pragma unroll
    for (int i = 0; i < 32; i += 8)
        tile[y + i][x] = W[(size_t)(kt + y + i) * N + nt + x];
    __syncthreads();
    #pragma unroll
    for (int i = 0; i < 32; i += 8)
        WT[(size_t)(nt + y + i) * K + kt + x] = f2bf(tile[x][y + i]);
}

// ---------------- fused q+kv GEMM + RMSNorm + RoPE + attention-layout pack ----------------
// Grid dim3(32, 24): blockIdx.x = m-block (XCD-localizes A panels), blockIdx.y = role/col.
__launch_bounds__(256, 3)
__global__ void k_gemm_qkv(const unsigned short* __restrict__ tgt_b,
                           const unsigned short* __restrict__ src_b,
                           const unsigned short* __restrict__ WqT,
                           const unsigned short* __restrict__ WkvT,
                           const float* __restrict__ tpos, const float* __restrict__ spos,
                           const float* __restrict__ qw, const float* __restrict__ kw,
                           unsigned short* __restrict__ q_a, unsigned short* __restrict__ k_f,
                           unsigned short* __restrict__ v_f) {
    __shared__ __align__(16) unsigned short As[128 * 64];
    __shared__ __align__(16) unsigned short Bs[128 * 64];
    const int tid  = threadIdx.x;
    const int wid  = tid >> 6, lane = tid & 63;
    const int l15  = lane & 15, l4 = lane >> 4;
    const int bx = blockIdx.y;                       // role/col selector
    const unsigned short* A;  const unsigned short* BT;  int n0;
    if (bx < 8) { A = tgt_b; BT = WqT;  n0 = bx * 128; }
    else        { A = src_b; BT = WkvT; n0 = (bx - 8) * 128; }
    const int K = DIM;
    const int m0 = blockIdx.x * 128;                 // m-block: XCD = blockIdx.x % 8
    const int wr = wid >> 1, wc = wid & 1;
    const int srow = lane >> 3, schunk = lane & 7;

    f32x4 acc[4][4] = {};

    for (int kt = 0; kt < K; kt += 64) {
        #pragma unroll
        for (int t = 0; t < 4; ++t) {
            int r  = (t * 4 + wid) * 8 + srow;          // tile row 0..127
            int ck = schunk ^ (r & 7);                  // pre-swizzled source chunk
            const unsigned short* ga = A  + (size_t)(m0 + r) * K + kt + ck * 8;
            const unsigned short* gb = BT + (size_t)(n0 + r) * K + kt + ck * 8;
            unsigned short* la = As + (t * 4 + wid) * 512 + lane * 8;  // linear dest
            unsigned short* lb = Bs + (t * 4 + wid) * 512 + lane * 8;
            __builtin_amdgcn_global_load_lds((const __attribute__((address_space(1))) void*)ga,
                                             (__attribute__((address_space(3))) void*)la, 16, 0, 0);
            __builtin_amdgcn_global_load_lds((const __attribute__((address_space(1))) void*)gb,
                                             (__attribute__((address_space(3))) void*)lb, 16, 0, 0);
        }
        __syncthreads();
        #pragma unroll
        for (int k0 = 0; k0 < 2; ++k0) {
            bf16x8 af[4], bfr[4];
            int kk = k0 * 32 + l4 * 8;
            #pragma unroll
            for (int i = 0; i < 4; ++i) {
                int ar = wr * 64 + i * 16 + l15;
                af[i]  = *(const bf16x8*)((const char*)As + ar * 128 + ((kk * 2) ^ ((ar & 7) << 4)));
                int br = wc * 64 + i * 16 + l15;
                bfr[i] = *(const bf16x8*)((const char*)Bs + br * 128 + ((kk * 2) ^ ((br & 7) << 4)));
            }
            #pragma unroll
            for (int i = 0; i < 4; ++i)
                #pragma unroll
                for (int j = 0; j < 4; ++j)
                    acc[i][j] = __builtin_amdgcn_mfma_f32_16x16x32_bf16(af[i], bfr[j], acc[i][j], 0, 0, 0);
        }
        __syncthreads();
    }

    // ---------- fused epilogue ----------
    const int colbase = n0 + wc * 64;                       // q/k: 0..1023 ; v: 1024..2047
    const int mode = (bx < 8) ? 0 : ((colbase < 1024) ? 1 : 2);

    if (mode == 2) {                                        // V: cast into fragment-linear v_f
        const int h = (colbase - 1024) >> 6;
        #pragma unroll
        for (int i = 0; i < 4; ++i)
            #pragma unroll
            for (int r = 0; r < 4; ++r) {
                int row = m0 + wr * 64 + i * 16 + l4 * 4 + r;
                int b = row >> 11, mm = row & (SEQ - 1);
                int bh = b * NH + h;
                int t = mm >> 6, ks = (mm >> 5) & 1, kc = (mm >> 4) & 1;
                int hiv = (mm >> 3) & 1, e = mm & 7;
                #pragma unroll
                for (int j = 0; j < 4; ++j) {
                    int dh = j >> 1, l31v = (j & 1) * 16 + l15;
                    size_t idx = (((((size_t)(bh * 32 + t) * 2 + ks) * 2 + kc) * 2 + dh) * 2 + hiv) * 256
                                 + l31v * 8 + e;
                    v_f[idx] = f2bf(acc[i][j][r]);
                }
            }
        return;
    }

    const float* pos = (mode == 0) ? tpos : spos;
    const float* wt  = (mode == 0) ? qw : kw;
    const int h = colbase >> 6;
    const float QS = (mode == 0) ? 0.18033688011112042f : 1.0f;  // log2(e)/8 folded into q
    const float eps = 1.1920928955078125e-7f;

    float w4[4];
    #pragma unroll
    for (int j = 0; j < 4; ++j) w4[j] = wt[j * 16 + l15];
    float invf0 = __expf(-(float)(2 * l15) * (1.0f / 64.0f) * 9.21034037198f);
    float invf1 = __expf(-(float)(2 * (16 + l15)) * (1.0f / 64.0f) * 9.21034037198f);

    #pragma unroll
    for (int i = 0; i < 4; ++i)
        #pragma unroll
        for (int r = 0; r < 4; ++r) {
            int row = m0 + wr * 64 + i * 16 + l4 * 4 + r;
            float v0 = acc[i][0][r], v1 = acc[i][1][r], v2 = acc[i][2][r], v3 = acc[i][3][r];
            float ssq = v0 * v0 + v1 * v1 + v2 * v2 + v3 * v3;
            ssq += __shfl_xor(ssq, 1, 64);
            ssq += __shfl_xor(ssq, 2, 64);
            ssq += __shfl_xor(ssq, 4, 64);
            ssq += __shfl_xor(ssq, 8, 64);
            float sc = rsqrtf(ssq * (1.0f / 64.0f) + eps);
            v0 *= sc * w4[0]; v1 *= sc * w4[1]; v2 *= sc * w4[2]; v3 *= sc * w4[3];
            float p = pos[row];
            float s0, c0, s1, c1;
            __sincosf(p * invf0, &s0, &c0);
            __sincosf(p * invf1, &s1, &c1);
            float o0 = (v0 * c0 - v2 * s0) * QS;    // d = l15
            float o1 = (v1 * c1 - v3 * s1) * QS;    // d = 16+l15
            float o2 = (v0 * s0 + v2 * c0) * QS;    // d = 32+l15
            float o3 = (v1 * s1 + v3 * c1) * QS;    // d = 48+l15
            int b = row >> 11, n = row & (SEQ - 1);
            if (mode == 0) {
                unsigned short* dst = q_a + ((size_t)(b * NH + h) * SEQ + n) * 64;
                dst[l15]      = f2bf(o0);
                dst[16 + l15] = f2bf(o1);
                dst[32 + l15] = f2bf(o2);
                dst[48 + l15] = f2bf(o3);
            } else {
                // K into fragment-linear k_f: idx((bh,t,ks,c,hi,l31,e)) ; d = j*16+l15
                int bh = b * NH + h;
                int t = n >> 6, ksn = (n >> 5) & 1, l31k = n & 31;
                int hik = l15 >> 3, e = l15 & 7;
                size_t base = ((size_t)(bh * 32 + t) * 2 + ksn) * 4;
                k_f[(base + 0) * 512 + hik * 256 + l31k * 8 + e] = f2bf(o0);
                k_f[(base + 1) * 512 + hik * 256 + l31k * 8 + e] = f2bf(o1);
                k_f[(base + 2) * 512 + hik * 256 + l31k * 8 + e] = f2bf(o2);
                k_f[(base + 3) * 512 + hik * 256 + l31k * 8 + e] = f2bf(o3);
            }
        }
}

// ---------------- o-GEMM: C[M][N] f32 = A[M][K] bf16 @ BT[N][K]^T ----------------
// Grid dim3(32, 8): blockIdx.x = m-block (XCD-localizes A panels).
__launch_bounds__(256)
__global__ void k_gemm_bt(const unsigned short* __restrict__ A,
                          const unsigned short* __restrict__ BT,
                          float* __restrict__ C, int M, int N, int K) {
    __shared__ __align__(16) unsigned short As[128 * 64];
    __shared__ __align__(16) unsigned short Bs[128 * 64];
    const int tid  = threadIdx.x;
    const int wid  = tid >> 6, lane = tid & 63;
    const int l15  = lane & 15, l4 = lane >> 4;
    const int m0 = blockIdx.x * 128, n0 = blockIdx.y * 128;
    const int wr = wid >> 1, wc = wid & 1;
    const int srow = lane >> 3, schunk = lane & 7;

    f32x4 acc[4][4] = {};

    for (int kt = 0; kt < K; kt += 64) {
        #pragma unroll
        for (int t = 0; t < 4; ++t) {
            int r  = (t * 4 + wid) * 8 + srow;
            int ck = schunk ^ (r & 7);
            const unsigned short* ga = A  + (size_t)(m0 + r) * K + kt + ck * 8;
            const unsigned short* gb = BT + (size_t)(n0 + r) * K + kt + ck * 8;
            unsigned short* la = As + (t * 4 + wid) * 512 + lane * 8;
            unsigned short* lb = Bs + (t * 4 + wid) * 512 + lane * 8;
            __builtin_amdgcn_global_load_lds((const __attribute__((address_space(1))) void*)ga,
                                             (__attribute__((address_space(3))) void*)la, 16, 0, 0);
            __builtin_amdgcn_global_load_lds((const __attribute__((address_space(1))) void*)gb,
                                             (__attribute__((address_space(3))) void*)lb, 16, 0, 0);
        }
        __syncthreads();
        #pragma unroll
        for (int k0 = 0; k0 < 2; ++k0) {
            bf16x8 af[4], bfr[4];
            int kk = k0 * 32 + l4 * 8;
            #pragma unroll
            for (int i = 0; i < 4; ++i) {
                int ar = wr * 64 + i * 16 + l15;
                af[i]  = *(const bf16x8*)((const char*)As + ar * 128 + ((kk * 2) ^ ((ar & 7) << 4)));
                int br = wc * 64 + i * 16 + l15;
                bfr[i] = *(const bf16x8*)((const char*)Bs + br * 128 + ((kk * 2) ^ ((br & 7) << 4)));
            }
            #pragma unroll
            for (int i = 0; i < 4; ++i)
                #pragma unroll
                for (int j = 0; j < 4; ++j)
                    acc[i][j] = __builtin_amdgcn_mfma_f32_16x16x32_bf16(af[i], bfr[j], acc[i][j], 0, 0, 0);
        }
        __syncthreads();
    }
    #pragma unroll
    for (int i = 0; i < 4; ++i) {
        int rb = m0 + wr * 64 + i * 16 + l4 * 4;
        #pragma unroll
        for (int j = 0; j < 4; ++j) {
            int col = n0 + wc * 64 + j * 16 + l15;
            #pragma unroll
            for (int r = 0; r < 4; ++r)
                C[(size_t)(rb + r) * N + col] = acc[i][j][r];
        }
    }
}

// ---------------- flash attention, fully fused (KV-split combined IN-BLOCK) ----------------
// v17 = verified R14 body exactly (best: attn ~43.6us). All inner-loop
// restructurings (manual dbuf, NS=4 x2, hand-T15, pragma-unroll-2) failed
// correctness or regressed; this rolled form is the kernel's local optimum.
// XCD-aligned grid (FETCH 12.4 MB, KV L2-resident).
__launch_bounds__(512, 2)
__global__ void k_attn_part(const unsigned short* __restrict__ q_a,
                            const unsigned short* __restrict__ k_f,
                            const unsigned short* __restrict__ v_f,
                            unsigned short* __restrict__ x_b) {
    __shared__ float LO[4][32][68];   // [pair][qrow][col]; cols 64..67 hold L: 64+2*qf+ns
    const int tid = threadIdx.x;
    const int wid = tid >> 6, lane = tid & 63;
    const int l31 = lane & 31, hi = lane >> 5;
    const int pid = wid & 3, ns = wid >> 2;
    const int blk = blockIdx.x;
    const int bh = blk & 31, qx = blk >> 5;   // bh in low 5 bits -> XCD-aligned
    const int q0 = qx * 256 + pid * 64;
    const unsigned short* qb = q_a + (size_t)bh * SEQ * 64;

    bf16x8 qfr[2][4];
    #pragma unroll
    for (int qf = 0; qf < 2; ++qf)
        #pragma unroll
        for (int c = 0; c < 4; ++c)
            qfr[qf][c] = *(const bf16x8*)(qb + (size_t)(q0 + qf * 32 + l31) * 64 + c * 16 + hi * 8);

    const bf16x8* kf8 = (const bf16x8*)k_f + ((size_t)bh * 32 + ns * NT) * 512;
    const bf16x8* vf8 = (const bf16x8*)v_f + ((size_t)bh * 32 + ns * NT) * 512;

    f32x16 oacc[2][2] = {};
    float lsum[2] = {0.f, 0.f};

    for (int t = 0; t < NT; ++t) {
        const bf16x8* kt = kf8 + (size_t)t * 512;
        const bf16x8* vt = vf8 + (size_t)t * 512;

        bf16x8 kf[2][4];
        #pragma unroll
        for (int ks = 0; ks < 2; ++ks)
            #pragma unroll
            for (int c = 0; c < 4; ++c)
                kf[ks][c] = kt[((ks * 4 + c) * 2 + hi) * 32 + l31];

        f32x16 sacc[2][2] = {};   // [qf][ks]
        #pragma unroll
        for (int ks = 0; ks < 2; ++ks)
            #pragma unroll
            for (int c = 0; c < 4; ++c) {
                sacc[0][ks] = __builtin_amdgcn_mfma_f32_32x32x16_bf16(kf[ks][c], qfr[0][c], sacc[0][ks], 0, 0, 0);
                sacc[1][ks] = __builtin_amdgcn_mfma_f32_32x32x16_bf16(kf[ks][c], qfr[1][c], sacc[1][ks], 0, 0, 0);
            }

        #pragma unroll
        for (int ks = 0; ks < 2; ++ks)
            #pragma unroll
            for (int kc = 0; kc < 2; ++kc) {
                bf16x8 vf[2];
                #pragma unroll
                for (int dh = 0; dh < 2; ++dh)
                    vf[dh] = vt[(((ks * 2 + kc) * 2 + dh) * 2 + hi) * 32 + l31];
                #pragma unroll
                for (int qf = 0; qf < 2; ++qf) {
                    float p[8];
                    #pragma unroll
                    for (int j = 0; j < 8; ++j)
                        p[j] = __builtin_amdgcn_exp2f(sacc[qf][ks][kc * 8 + j]);
                    lsum[qf] += ((p[0] + p[1]) + (p[2] + p[3])) + ((p[4] + p[5]) + (p[6] + p[7]));
                    unsigned a0 = cvt_pk_bf16(p[0], p[1]);
                    unsigned a1 = cvt_pk_bf16(p[2], p[3]);
                    unsigned b0 = cvt_pk_bf16(p[4], p[5]);
                    unsigned b1 = cvt_pk_bf16(p[6], p[7]);
                    asm("v_permlane32_swap_b32 %0, %1" : "+v"(a0), "+v"(b0));
                    asm("v_permlane32_swap_b32 %0, %1" : "+v"(a1), "+v"(b1));
                    u32x4 w; w.x = a0; w.y = a1; w.z = b0; w.w = b1;
                    bf16x8 pa = __builtin_bit_cast(bf16x8, w);
                    #pragma unroll
                    for (int dh = 0; dh < 2; ++dh)
                        oacc[qf][dh] = __builtin_amdgcn_mfma_f32_32x32x16_bf16(pa, vf[dh], oacc[qf][dh], 0, 0, 0);
                }
            }
    }

    lsum[0] += __shfl_xor(lsum[0], 32, 64);
    lsum[1] += __shfl_xor(lsum[1], 32, 64);

    // ---- in-block NS combine ----
    if (hi == 0) {
        LO[pid][l31][64 + ns] = lsum[0];
        LO[pid][l31][66 + ns] = lsum[1];
    }
    const int b_ = bh >> 4, h_ = bh & 15;
    #pragma unroll
    for (int qf = 0; qf < 2; ++qf) {
        __syncthreads();
        if (ns == 1) {
            #pragma unroll
            for (int r = 0; r < 16; ++r) {
                int qrow = (r & 3) + 8 * (r >> 2) + 4 * hi;
                LO[pid][qrow][l31]      = oacc[qf][0][r];
                LO[pid][qrow][32 + l31] = oacc[qf][1][r];
            }
        }
        __syncthreads();
        if (ns == 0) {
            #pragma unroll
            for (int r = 0; r < 16; ++r) {
                int qrow = (r & 3) + 8 * (r >> 2) + 4 * hi;
                float Lt = LO[pid][qrow][64 + 2 * qf] + LO[pid][qrow][65 + 2 * qf];
                float rec = 1.0f / Lt;
                float o0 = (oacc[qf][0][r] + LO[pid][qrow][l31])      * rec;
                float o1 = (oacc[qf][1][r] + LO[pid][qrow][32 + l31]) * rec;
                int q = q0 + qf * 32 + qrow;
                unsigned short* dst = x_b + ((size_t)(b_ * SEQ + q)) * DIM + h_ * 64;
                dst[l31]      = f2bf(o0);
                dst[32 + l31] = f2bf(o1);
            }
        }
    }
}

extern "C" void kernel_launch(void* const* d_in, const int* in_sizes, int n_in,
                              void* d_out, int out_size, void* d_ws, size_t ws_size,
                              hipStream_t stream) {
    const float* tgt  = (const float*)d_in[0];
    const float* src  = (const float*)d_in[1];
    const float* tpos = (const float*)d_in[2];
    const float* spos = (const float*)d_in[3];
    const float* Wq   = (const float*)d_in[4];
    const float* Wkv  = (const float*)d_in[5];
    const float* Wo   = (const float*)d_in[6];
    const float* qw   = (const float*)d_in[7];
    const float* kw   = (const float*)d_in[8];
    float* out = (float*)d_out;
    char* ws = (char*)d_ws;

    // workspace map (MB): [0,8) x_b|tgt_b  [8,16) src_b  [16,18) WqT  [18,22) WkvT
    // [22,24) WoT  [88,96) q_a  [96,104) k_f  [104,112) v_f
    unsigned short* tgt_b = (unsigned short*)(ws);
    unsigned short* src_b = (unsigned short*)(ws + ( 8u << 20));
    unsigned short* WqT   = (unsigned short*)(ws + (16u << 20));
    unsigned short* WkvT  = (unsigned short*)(ws + (18u << 20));
    unsigned short* WoT   = (unsigned short*)(ws + (22u << 20));
    unsigned short* q_a   = (unsigned short*)(ws + (88u << 20));
    unsigned short* k_f   = (unsigned short*)(ws + (96u << 20));
    unsigned short* v_f   = (unsigned short*)(ws + (104u << 20));
    unsigned short* x_b   = (unsigned short*)(ws);                 // alias tgt_b (dead)

    k_pre<<<12288, 256, 0, stream>>>(tgt, src, tgt_b, src_b, Wq, Wkv, Wo, WqT, WkvT, WoT);
    k_gemm_qkv<<<dim3(32, 24), 256, 0, stream>>>(tgt_b, src_b, WqT, WkvT,
                                                 tpos, spos, qw, kw, q_a, k_f, v_f);
    k_attn_part<<<256, 512, 0, stream>>>(q_a, k_f, v_f, x_b);
    k_gemm_bt<<<dim3(32, 8), 256, 0, stream>>>(x_b, WoT, out, ROWS, DIM, DIM);
}